// Round 1
// baseline (5599.847 us; speedup 1.0000x reference)
//
#include <hip/hip_runtime.h>

#define HID 100
#define TT  1024
#define BPW 4     // batches per workgroup
#define WPL 64    // workgroups per LSTM (64*4 = 256 batches)

__device__ __forceinline__ float sigf(float x) { return 1.f / (1.f + __expf(-x)); }
__device__ __forceinline__ float tanhf_fast(float x) { return 2.f / (1.f + __expf(-2.f * x)) - 1.f; }

// One WG = 4 batch chains of one LSTM. 200 "gate" threads each own 2 of the 400
// gate rows (rows t and t+200) with W_hh held entirely in registers (200 VGPRs;
// gfx950 unified 512-reg file). h is broadcast from LDS (uniform-address
// ds_read_b128 = conflict-free). Gates staged slot-major [b][4][100] so writes
// (consecutive cell) and reads (consecutive n, 4 strided b32) are conflict-free.
// Cell state c lives in registers of a statically-mapped update thread.
__global__ __launch_bounds__(256, 1) void lstm3_kernel(
    const float* __restrict__ x1, const float* __restrict__ x2, const float* __restrict__ x3,
    const float* __restrict__ Wih1, const float* __restrict__ Whh1, const float* __restrict__ bi1, const float* __restrict__ bh1,
    const float* __restrict__ Wih2, const float* __restrict__ Whh2, const float* __restrict__ bi2, const float* __restrict__ bh2,
    const float* __restrict__ Wih3, const float* __restrict__ Whh3, const float* __restrict__ bi3, const float* __restrict__ bh3,
    float* __restrict__ hws)
{
    const int wg    = blockIdx.x;
    const int L     = wg / WPL;
    const int bbase = (wg % WPL) * BPW;
    const int tid   = threadIdx.x;

    const float* x   = (L == 0) ? x1   : (L == 1) ? x2   : x3;
    const float* Wih = (L == 0) ? Wih1 : (L == 1) ? Wih2 : Wih3;
    const float* Whh = (L == 0) ? Whh1 : (L == 1) ? Whh2 : Whh3;
    const float* bi  = (L == 0) ? bi1  : (L == 1) ? bi2  : bi3;
    const float* bh  = (L == 0) ? bh1  : (L == 1) ? bh2  : bh3;

    __shared__ __align__(16) float h_lds[2][BPW][HID];   // double-buffered h
    __shared__ __align__(16) float g_lds[BPW][4][HID];   // gates, slot-major

    // zero h buffer 0 (h_0 = 0)
    for (int i = tid; i < BPW * HID; i += 256) ((float*)h_lds[0])[i] = 0.f;

    // ---- gate-thread setup: 2 rows of W_hh in registers ----
    const bool gth  = tid < 200;
    const int  cell = tid % 100;            // loop-invariant
    const int  s0   = (tid < 100) ? 0 : 1;  // slot of first owned row (i or f)

    float w[2][HID];
    float wih[2][4];
    float bias[2];
    if (gth) {
#pragma unroll
        for (int r = 0; r < 2; r++) {
            const int row = tid + r * 200;  // rows t (i/f) and t+200 (g/o)
            const float4* wp = (const float4*)(Whh + row * HID);
#pragma unroll
            for (int c2 = 0; c2 < 25; c2++) {
                float4 v = wp[c2];
                w[r][c2 * 4 + 0] = v.x; w[r][c2 * 4 + 1] = v.y;
                w[r][c2 * 4 + 2] = v.z; w[r][c2 * 4 + 3] = v.w;
            }
            const float4 wi = *(const float4*)(Wih + row * 4);
            wih[r][0] = wi.x; wih[r][1] = wi.y; wih[r][2] = wi.z; wih[r][3] = wi.w;
            bias[r] = bi[row] + bh[row];
        }
    }

    // ---- update-thread setup: static job -> (b, n); c kept in registers ----
    const int  j0  = tid;               // job 0: always valid (tid < 256 < 400)
    const int  b0j = j0 / 100, n0 = j0 % 100;
    const bool j1v = tid < 144;         // 400 = 256 + 144
    const int  j1  = tid + 256;
    const int  b1j = j1 / 100, n1 = j1 % 100;
    float cc0 = 0.f, cc1 = 0.f, hh0 = 0.f, hh1 = 0.f;

    // x prefetch for step 0 (uniform address, one float4 per batch)
    float4 xv[BPW];
#pragma unroll
    for (int b = 0; b < BPW; b++)
        xv[b] = *(const float4*)(x + ((bbase + b) * TT + 0) * 4);

    __syncthreads();

#pragma unroll 1
    for (int st = 0; st < TT; ++st) {
        const int pr = st & 1;

        float acc[2][BPW];
        if (gth) {
#pragma unroll
            for (int r = 0; r < 2; r++)
#pragma unroll
                for (int b = 0; b < BPW; b++)
                    acc[r][b] = bias[r] + wih[r][0] * xv[b].x + wih[r][1] * xv[b].y
                              + wih[r][2] * xv[b].z + wih[r][3] * xv[b].w;
        }

        // prefetch next step's x (overwrites xv after last use; latency hidden
        // under the FMA loop). Clamp last step to avoid OOB.
        {
            const int nst = (st < TT - 1) ? st + 1 : st;
#pragma unroll
            for (int b = 0; b < BPW; b++)
                xv[b] = *(const float4*)(x + ((bbase + b) * TT + nst) * 4);
        }

        if (gth) {
            // main recurrent GEMV: acc[r][b] += sum_k w[r][k] * h[b][k]
#pragma unroll
            for (int c2 = 0; c2 < 25; c2++) {
                float4 hv[BPW];
#pragma unroll
                for (int b = 0; b < BPW; b++)
                    hv[b] = *(const float4*)&h_lds[pr][b][c2 * 4];
#pragma unroll
                for (int b = 0; b < BPW; b++) {
                    acc[0][b] += w[0][c2 * 4 + 0] * hv[b].x;
                    acc[0][b] += w[0][c2 * 4 + 1] * hv[b].y;
                    acc[0][b] += w[0][c2 * 4 + 2] * hv[b].z;
                    acc[0][b] += w[0][c2 * 4 + 3] * hv[b].w;
                    acc[1][b] += w[1][c2 * 4 + 0] * hv[b].x;
                    acc[1][b] += w[1][c2 * 4 + 1] * hv[b].y;
                    acc[1][b] += w[1][c2 * 4 + 2] * hv[b].z;
                    acc[1][b] += w[1][c2 * 4 + 3] * hv[b].w;
                }
            }
            // stage gates (conflict-free: consecutive lanes -> consecutive cell)
#pragma unroll
            for (int b = 0; b < BPW; b++) {
                g_lds[b][s0][cell]     = acc[0][b];
                g_lds[b][s0 + 2][cell] = acc[1][b];
            }
        }
        __syncthreads();

        // ---- cell update (i,f,g,o -> c,h), h written to other buffer ----
        {
            const float gi = g_lds[b0j][0][n0];
            const float gf = g_lds[b0j][1][n0];
            const float gg = g_lds[b0j][2][n0];
            const float go = g_lds[b0j][3][n0];
            cc0 = sigf(gf) * cc0 + sigf(gi) * tanhf_fast(gg);
            hh0 = sigf(go) * tanhf_fast(cc0);
            h_lds[pr ^ 1][b0j][n0] = hh0;
            if (j1v) {
                const float gi1 = g_lds[b1j][0][n1];
                const float gf1 = g_lds[b1j][1][n1];
                const float gg1 = g_lds[b1j][2][n1];
                const float go1 = g_lds[b1j][3][n1];
                cc1 = sigf(gf1) * cc1 + sigf(gi1) * tanhf_fast(gg1);
                hh1 = sigf(go1) * tanhf_fast(cc1);
                h_lds[pr ^ 1][b1j][n1] = hh1;
            }
        }
        __syncthreads();
    }

    // final h -> workspace, laid out [b_global][300] with column L*100+n
    hws[(bbase + b0j) * 300 + L * HID + n0] = hh0;
    if (j1v) hws[(bbase + b1j) * 300 + L * HID + n1] = hh1;
}

// out[b][o] = relu(fc_b[o] + sum_j h[b][j] * fc_W[o][j]),  j < 300, o < 12
__global__ __launch_bounds__(64, 1) void fc_kernel(
    const float* __restrict__ hws, const float* __restrict__ fcW,
    const float* __restrict__ fcb, float* __restrict__ out)
{
    const int b = blockIdx.x, lane = threadIdx.x;
    float hv[5];
#pragma unroll
    for (int c = 0; c < 5; c++) {
        const int j = lane + 64 * c;
        hv[c] = (j < 300) ? hws[b * 300 + j] : 0.f;
    }
#pragma unroll
    for (int o = 0; o < 12; o++) {
        float a = 0.f;
#pragma unroll
        for (int c = 0; c < 5; c++) {
            const int j = lane + 64 * c;
            const float wv = (j < 300) ? fcW[o * 300 + j] : 0.f;
            a += hv[c] * wv;
        }
#pragma unroll
        for (int off = 32; off > 0; off >>= 1) a += __shfl_xor(a, off, 64);
        if (lane == 0) out[b * 12 + o] = fmaxf(a + fcb[o], 0.f);
    }
}

extern "C" void kernel_launch(void* const* d_in, const int* in_sizes, int n_in,
                              void* d_out, int out_size, void* d_ws, size_t ws_size,
                              hipStream_t stream)
{
    const float* x1   = (const float*)d_in[0];
    const float* x2   = (const float*)d_in[1];
    const float* x3   = (const float*)d_in[2];
    const float* Wih1 = (const float*)d_in[3];
    const float* Whh1 = (const float*)d_in[4];
    const float* bi1  = (const float*)d_in[5];
    const float* bh1  = (const float*)d_in[6];
    const float* Wih2 = (const float*)d_in[7];
    const float* Whh2 = (const float*)d_in[8];
    const float* bi2  = (const float*)d_in[9];
    const float* bh2  = (const float*)d_in[10];
    const float* Wih3 = (const float*)d_in[11];
    const float* Whh3 = (const float*)d_in[12];
    const float* bi3  = (const float*)d_in[13];
    const float* bh3  = (const float*)d_in[14];
    const float* fcW  = (const float*)d_in[15];
    const float* fcb  = (const float*)d_in[16];

    float* hws = (float*)d_ws;  // 256*300 floats = 300 KiB

    lstm3_kernel<<<3 * WPL, 256, 0, stream>>>(x1, x2, x3,
                                              Wih1, Whh1, bi1, bh1,
                                              Wih2, Whh2, bi2, bh2,
                                              Wih3, Whh3, bi3, bh3, hws);
    fc_kernel<<<256, 64, 0, stream>>>(hws, fcW, fcb, (float*)d_out);
}

// Round 2
// 3999.721 us; speedup vs baseline: 1.4001x; 1.4001x over previous
//
#include <hip/hip_runtime.h>

#define HID 100
#define TT  1024
#define BPW 3     // batches per workgroup
#define WPL 86    // workgroups per LSTM (85 full + 1 tail) -> grid 258
#define NTHR 512

__device__ __forceinline__ float sigf(float x) { return 1.f / (1.f + __expf(-x)); }
__device__ __forceinline__ float tanhf_fast(float x) { return 2.f / (1.f + __expf(-2.f * x)) - 1.f; }

// One WG = 3 batch chains of one LSTM, 512 threads (8 waves).
// - x slab preloaded to LDS once -> ZERO global loads in the 1024-step loop,
//   so the compiler's vmcnt(0)-before-barrier drains nothing (R0's stall #1).
// - Each wave's lanes 0-49 own one W_hh row (row = wave*50+lane) in 100 VGPRs;
//   all 8 waves issue identical FMA streams -> SIMD-balanced, 2 waves/SIMD.
// - h broadcast from LDS (uniform-address ds_read_b128 = conflict-free);
//   gates staged slot-major; c lives in registers of a static update thread.
__global__ __launch_bounds__(NTHR, 1) void lstm3_kernel(
    const float* __restrict__ x1, const float* __restrict__ x2, const float* __restrict__ x3,
    const float* __restrict__ Wih1, const float* __restrict__ Whh1, const float* __restrict__ bi1, const float* __restrict__ bh1,
    const float* __restrict__ Wih2, const float* __restrict__ Whh2, const float* __restrict__ bi2, const float* __restrict__ bh2,
    const float* __restrict__ Wih3, const float* __restrict__ Whh3, const float* __restrict__ bi3, const float* __restrict__ bh3,
    float* __restrict__ hws)
{
    const int wg    = blockIdx.x;
    const int L     = wg / WPL;
    const int bbase = (wg % WPL) * BPW;   // 0..255 (last WG: 255 -> 1 real batch)
    const int tid   = threadIdx.x;

    const float* x   = (L == 0) ? x1   : (L == 1) ? x2   : x3;
    const float* Wih = (L == 0) ? Wih1 : (L == 1) ? Wih2 : Wih3;
    const float* Whh = (L == 0) ? Whh1 : (L == 1) ? Whh2 : Whh3;
    const float* bi  = (L == 0) ? bi1  : (L == 1) ? bi2  : bi3;
    const float* bh  = (L == 0) ? bh1  : (L == 1) ? bh2  : bh3;

    __shared__ __align__(16) float x_lds[BPW][TT][4];   // 48 KiB
    __shared__ __align__(16) float h_lds[2][BPW][HID];  // 2.4 KiB (double-buffered)
    __shared__ __align__(16) float g_lds[BPW][4][HID];  // 4.8 KiB (slot-major)

    // ---- one-time x slab preload (coalesced float4; tail WG clamps batch) ----
    for (int i = tid; i < BPW * TT; i += NTHR) {
        const int b  = i / TT, t = i % TT;
        const int bg = min(bbase + b, 255);
        ((float4*)x_lds)[i] = *(const float4*)(x + (bg * TT + t) * 4);
    }
    // h_0 = 0
    for (int i = tid; i < BPW * HID; i += NTHR) ((float*)h_lds[0])[i] = 0.f;

    // ---- gate-thread setup: one W_hh row in registers ----
    const int  wave = tid >> 6, lane = tid & 63;
    const bool gth  = lane < 50;
    const int  row  = wave * 50 + lane;          // 0..399 when gth
    const int  slot = row / 100, cell = row % 100;

    float w[HID];
    float wih0 = 0, wih1 = 0, wih2 = 0, wih3 = 0, bias = 0;
    if (gth) {
        const float4* wp = (const float4*)(Whh + row * HID);
#pragma unroll
        for (int c = 0; c < 25; c++) {
            const float4 v = wp[c];
            w[4 * c + 0] = v.x; w[4 * c + 1] = v.y;
            w[4 * c + 2] = v.z; w[4 * c + 3] = v.w;
        }
        const float4 wi = *(const float4*)(Wih + row * 4);
        wih0 = wi.x; wih1 = wi.y; wih2 = wi.z; wih3 = wi.w;
        bias = bi[row] + bh[row];
    }

    // ---- update-thread setup: 300 jobs spread over all 8 waves (38/wave) ----
    const int  uj  = wave * 38 + lane;           // lane<38
    const bool uth = (lane < 38) && (uj < 300);
    const int  ub  = uth ? uj / 100 : 0;
    const int  un  = uth ? uj % 100 : 0;
    float cc = 0.f, hh = 0.f;

    __syncthreads();

#pragma unroll 1
    for (int st = 0; st < TT; ++st) {
        const int cur = st & 1;

        if (gth) {
            const float4 xb0 = *(const float4*)&x_lds[0][st][0];
            const float4 xb1 = *(const float4*)&x_lds[1][st][0];
            const float4 xb2 = *(const float4*)&x_lds[2][st][0];
            float a0 = bias + wih0 * xb0.x + wih1 * xb0.y + wih2 * xb0.z + wih3 * xb0.w;
            float a1 = bias + wih0 * xb1.x + wih1 * xb1.y + wih2 * xb1.z + wih3 * xb1.w;
            float a2 = bias + wih0 * xb2.x + wih1 * xb2.y + wih2 * xb2.z + wih3 * xb2.w;

#pragma unroll
            for (int c = 0; c < 25; c++) {
                const float4 h0 = *(const float4*)&h_lds[cur][0][4 * c];
                const float4 h1 = *(const float4*)&h_lds[cur][1][4 * c];
                const float4 h2 = *(const float4*)&h_lds[cur][2][4 * c];
                const float w0 = w[4 * c + 0], w1 = w[4 * c + 1];
                const float w2 = w[4 * c + 2], w3 = w[4 * c + 3];
                a0 += w0 * h0.x; a0 += w1 * h0.y; a0 += w2 * h0.z; a0 += w3 * h0.w;
                a1 += w0 * h1.x; a1 += w1 * h1.y; a1 += w2 * h1.z; a1 += w3 * h1.w;
                a2 += w0 * h2.x; a2 += w1 * h2.y; a2 += w2 * h2.z; a2 += w3 * h2.w;
            }
            g_lds[0][slot][cell] = a0;
            g_lds[1][slot][cell] = a1;
            g_lds[2][slot][cell] = a2;
        }
        __syncthreads();

        if (uth) {
            const float gi = g_lds[ub][0][un];
            const float gf = g_lds[ub][1][un];
            const float gg = g_lds[ub][2][un];
            const float go = g_lds[ub][3][un];
            cc = sigf(gf) * cc + sigf(gi) * tanhf_fast(gg);
            hh = sigf(go) * tanhf_fast(cc);
            h_lds[cur ^ 1][ub][un] = hh;
        }
        __syncthreads();
    }

    // final h -> workspace [b_global][300], column L*100 + n
    if (uth) {
        const int bg = bbase + ub;
        if (bg < 256) hws[bg * 300 + L * HID + un] = hh;
    }
}

// out[b][o] = relu(fc_b[o] + sum_j h[b][j] * fc_W[o][j]),  j < 300, o < 12
__global__ __launch_bounds__(64, 1) void fc_kernel(
    const float* __restrict__ hws, const float* __restrict__ fcW,
    const float* __restrict__ fcb, float* __restrict__ out)
{
    const int b = blockIdx.x, lane = threadIdx.x;
    float hv[5];
#pragma unroll
    for (int c = 0; c < 5; c++) {
        const int j = lane + 64 * c;
        hv[c] = (j < 300) ? hws[b * 300 + j] : 0.f;
    }
#pragma unroll
    for (int o = 0; o < 12; o++) {
        float a = 0.f;
#pragma unroll
        for (int c = 0; c < 5; c++) {
            const int j = lane + 64 * c;
            const float wv = (j < 300) ? fcW[o * 300 + j] : 0.f;
            a += hv[c] * wv;
        }
#pragma unroll
        for (int off = 32; off > 0; off >>= 1) a += __shfl_xor(a, off, 64);
        if (lane == 0) out[b * 12 + o] = fmaxf(a + fcb[o], 0.f);
    }
}

extern "C" void kernel_launch(void* const* d_in, const int* in_sizes, int n_in,
                              void* d_out, int out_size, void* d_ws, size_t ws_size,
                              hipStream_t stream)
{
    const float* x1   = (const float*)d_in[0];
    const float* x2   = (const float*)d_in[1];
    const float* x3   = (const float*)d_in[2];
    const float* Wih1 = (const float*)d_in[3];
    const float* Whh1 = (const float*)d_in[4];
    const float* bi1  = (const float*)d_in[5];
    const float* bh1  = (const float*)d_in[6];
    const float* Wih2 = (const float*)d_in[7];
    const float* Whh2 = (const float*)d_in[8];
    const float* bi2  = (const float*)d_in[9];
    const float* bh2  = (const float*)d_in[10];
    const float* Wih3 = (const float*)d_in[11];
    const float* Whh3 = (const float*)d_in[12];
    const float* bi3  = (const float*)d_in[13];
    const float* bh3  = (const float*)d_in[14];
    const float* fcW  = (const float*)d_in[15];
    const float* fcb  = (const float*)d_in[16];

    float* hws = (float*)d_ws;  // 256*300 floats = 300 KiB

    lstm3_kernel<<<3 * WPL, NTHR, 0, stream>>>(x1, x2, x3,
                                               Wih1, Whh1, bi1, bh1,
                                               Wih2, Whh2, bi2, bh2,
                                               Wih3, Whh3, bi3, bh3, hws);
    fc_kernel<<<256, 64, 0, stream>>>(hws, fcW, fcb, (float*)d_out);
}

// Round 3
// 2573.028 us; speedup vs baseline: 2.1764x; 1.5545x over previous
//
#include <hip/hip_runtime.h>

#define HID 100
#define TT  1024
#define BPW 4     // batches per workgroup (4*64 = 256 exactly -> no tail, no stragglers)
#define WPL 64    // workgroups per LSTM
#define NTHR 512

__device__ __forceinline__ float sigf(float x) { return 1.f / (1.f + __expf(-x)); }
__device__ __forceinline__ float tanhf_fast(float x) { return 2.f / (1.f + __expf(-2.f * x)) - 1.f; }

// One WG = 4 batch chains of one LSTM, 512 threads (8 waves), grid 192 (uniform).
// - W_hh row held in 25 NAMED float4 registers (W0..W24), loaded unconditionally
//   -> cannot be demoted to scratch (R1: VGPR=68 proved the array version was).
// - x slab preloaded to LDS once -> zero global loads in the recurrent loop.
// - h broadcast from LDS (uniform-address float4 = conflict-free broadcast).
// - Gate rows: wave w, lane l<50 owns row w*50+l. Update jobs reuse the same
//   lanes: (batch, cell) = (row/100, row%100) -- 400 jobs = BPW*HID exactly.
__global__ __launch_bounds__(NTHR, 1) void lstm3_kernel(
    const float* __restrict__ x1, const float* __restrict__ x2, const float* __restrict__ x3,
    const float* __restrict__ Wih1, const float* __restrict__ Whh1, const float* __restrict__ bi1, const float* __restrict__ bh1,
    const float* __restrict__ Wih2, const float* __restrict__ Whh2, const float* __restrict__ bi2, const float* __restrict__ bh2,
    const float* __restrict__ Wih3, const float* __restrict__ Whh3, const float* __restrict__ bi3, const float* __restrict__ bh3,
    float* __restrict__ hws)
{
    const int wg    = blockIdx.x;
    const int L     = wg / WPL;
    const int bbase = (wg % WPL) * BPW;
    const int tid   = threadIdx.x;

    const float* x   = (L == 0) ? x1   : (L == 1) ? x2   : x3;
    const float* Wih = (L == 0) ? Wih1 : (L == 1) ? Wih2 : Wih3;
    const float* Whh = (L == 0) ? Whh1 : (L == 1) ? Whh2 : Whh3;
    const float* bi  = (L == 0) ? bi1  : (L == 1) ? bi2  : bi3;
    const float* bh  = (L == 0) ? bh1  : (L == 1) ? bh2  : bh3;

    __shared__ __align__(16) float x_lds[BPW][TT][4];   // 64 KiB
    __shared__ __align__(16) float h_lds[2][BPW][HID];  // 3.2 KiB double-buffered
    __shared__ __align__(16) float g_lds[BPW][4][HID];  // 6.4 KiB slot-major

    // ---- one-time x slab preload (coalesced float4) ----
    for (int i = tid; i < BPW * TT; i += NTHR) {
        const int b = i / TT, t = i % TT;
        ((float4*)x_lds)[i] = *(const float4*)(x + ((size_t)(bbase + b) * TT + t) * 4);
    }
    for (int i = tid; i < BPW * HID; i += NTHR) ((float*)h_lds[0])[i] = 0.f;

    // ---- row ownership ----
    const int  wave = tid >> 6, lane = tid & 63;
    const bool gth  = lane < 50;
    const int  row  = wave * 50 + lane;          // semantic row (only valid if gth)
    const int  rowc = wave * 50 + min(lane, 49); // clamped row for safe loads
    const int  slot = row / 100;                 // gate slot / update batch (0..3)
    const int  cell = row % 100;                 // cell index  / update cell

    // ---- W_hh row in 25 NAMED float4 registers, unconditional loads ----
    const float4* wp = (const float4*)(Whh + (size_t)rowc * HID);
    const float4 W0  = wp[0],  W1  = wp[1],  W2  = wp[2],  W3  = wp[3],  W4  = wp[4];
    const float4 W5  = wp[5],  W6  = wp[6],  W7  = wp[7],  W8  = wp[8],  W9  = wp[9];
    const float4 W10 = wp[10], W11 = wp[11], W12 = wp[12], W13 = wp[13], W14 = wp[14];
    const float4 W15 = wp[15], W16 = wp[16], W17 = wp[17], W18 = wp[18], W19 = wp[19];
    const float4 W20 = wp[20], W21 = wp[21], W22 = wp[22], W23 = wp[23], W24 = wp[24];

    const float4 wi   = *(const float4*)(Wih + (size_t)rowc * 4);
    const float  bias = bi[rowc] + bh[rowc];

    float cc = 0.f, hh = 0.f;   // cell/hidden state of update job (slot, cell)

    __syncthreads();

#define GSTEP(C, WV) do {                                              \
        const float4 h0_ = *(const float4*)&h_lds[cur][0][4*(C)];      \
        const float4 h1_ = *(const float4*)&h_lds[cur][1][4*(C)];      \
        const float4 h2_ = *(const float4*)&h_lds[cur][2][4*(C)];      \
        const float4 h3_ = *(const float4*)&h_lds[cur][3][4*(C)];      \
        a0 += WV.x * h0_.x; a0 += WV.y * h0_.y; a0 += WV.z * h0_.z; a0 += WV.w * h0_.w; \
        a1 += WV.x * h1_.x; a1 += WV.y * h1_.y; a1 += WV.z * h1_.z; a1 += WV.w * h1_.w; \
        a2 += WV.x * h2_.x; a2 += WV.y * h2_.y; a2 += WV.z * h2_.z; a2 += WV.w * h2_.w; \
        a3 += WV.x * h3_.x; a3 += WV.y * h3_.y; a3 += WV.z * h3_.z; a3 += WV.w * h3_.w; \
    } while (0)

#pragma unroll 1
    for (int st = 0; st < TT; ++st) {
        const int cur = st & 1;

        // gate accumulators: bias + x-projection (x broadcast from LDS)
        const float4 xb0 = *(const float4*)&x_lds[0][st][0];
        const float4 xb1 = *(const float4*)&x_lds[1][st][0];
        const float4 xb2 = *(const float4*)&x_lds[2][st][0];
        const float4 xb3 = *(const float4*)&x_lds[3][st][0];
        float a0 = bias + wi.x * xb0.x + wi.y * xb0.y + wi.z * xb0.z + wi.w * xb0.w;
        float a1 = bias + wi.x * xb1.x + wi.y * xb1.y + wi.z * xb1.z + wi.w * xb1.w;
        float a2 = bias + wi.x * xb2.x + wi.y * xb2.y + wi.z * xb2.z + wi.w * xb2.w;
        float a3 = bias + wi.x * xb3.x + wi.y * xb3.y + wi.z * xb3.z + wi.w * xb3.w;

        GSTEP(0,  W0);  GSTEP(1,  W1);  GSTEP(2,  W2);  GSTEP(3,  W3);  GSTEP(4,  W4);
        GSTEP(5,  W5);  GSTEP(6,  W6);  GSTEP(7,  W7);  GSTEP(8,  W8);  GSTEP(9,  W9);
        GSTEP(10, W10); GSTEP(11, W11); GSTEP(12, W12); GSTEP(13, W13); GSTEP(14, W14);
        GSTEP(15, W15); GSTEP(16, W16); GSTEP(17, W17); GSTEP(18, W18); GSTEP(19, W19);
        GSTEP(20, W20); GSTEP(21, W21); GSTEP(22, W22); GSTEP(23, W23); GSTEP(24, W24);

        if (gth) {
            g_lds[0][slot][cell] = a0;
            g_lds[1][slot][cell] = a1;
            g_lds[2][slot][cell] = a2;
            g_lds[3][slot][cell] = a3;
        }
        __syncthreads();

        // ---- cell update: job (batch=slot, cell) on the same lanes ----
        if (gth) {
            const float gi = g_lds[slot][0][cell];
            const float gf = g_lds[slot][1][cell];
            const float gg = g_lds[slot][2][cell];
            const float go = g_lds[slot][3][cell];
            cc = sigf(gf) * cc + sigf(gi) * tanhf_fast(gg);
            hh = sigf(go) * tanhf_fast(cc);
            h_lds[cur ^ 1][slot][cell] = hh;
        }
        __syncthreads();
    }
#undef GSTEP

    // final h -> workspace [b_global][300], column L*100 + cell
    if (gth) hws[(size_t)(bbase + slot) * 300 + L * HID + cell] = hh;
}

// out[b][o] = relu(fc_b[o] + sum_j h[b][j] * fc_W[o][j]),  j < 300, o < 12
__global__ __launch_bounds__(64, 1) void fc_kernel(
    const float* __restrict__ hws, const float* __restrict__ fcW,
    const float* __restrict__ fcb, float* __restrict__ out)
{
    const int b = blockIdx.x, lane = threadIdx.x;
    float hv[5];
#pragma unroll
    for (int c = 0; c < 5; c++) {
        const int j = lane + 64 * c;
        hv[c] = (j < 300) ? hws[b * 300 + j] : 0.f;
    }
#pragma unroll
    for (int o = 0; o < 12; o++) {
        float a = 0.f;
#pragma unroll
        for (int c = 0; c < 5; c++) {
            const int j = lane + 64 * c;
            const float wv = (j < 300) ? fcW[o * 300 + j] : 0.f;
            a += hv[c] * wv;
        }
#pragma unroll
        for (int off = 32; off > 0; off >>= 1) a += __shfl_xor(a, off, 64);
        if (lane == 0) out[b * 12 + o] = fmaxf(a + fcb[o], 0.f);
    }
}

extern "C" void kernel_launch(void* const* d_in, const int* in_sizes, int n_in,
                              void* d_out, int out_size, void* d_ws, size_t ws_size,
                              hipStream_t stream)
{
    const float* x1   = (const float*)d_in[0];
    const float* x2   = (const float*)d_in[1];
    const float* x3   = (const float*)d_in[2];
    const float* Wih1 = (const float*)d_in[3];
    const float* Whh1 = (const float*)d_in[4];
    const float* bi1  = (const float*)d_in[5];
    const float* bh1  = (const float*)d_in[6];
    const float* Wih2 = (const float*)d_in[7];
    const float* Whh2 = (const float*)d_in[8];
    const float* bi2  = (const float*)d_in[9];
    const float* bh2  = (const float*)d_in[10];
    const float* Wih3 = (const float*)d_in[11];
    const float* Whh3 = (const float*)d_in[12];
    const float* bi3  = (const float*)d_in[13];
    const float* bh3  = (const float*)d_in[14];
    const float* fcW  = (const float*)d_in[15];
    const float* fcb  = (const float*)d_in[16];

    float* hws = (float*)d_ws;  // 256*300 floats = 300 KiB

    lstm3_kernel<<<3 * WPL, NTHR, 0, stream>>>(x1, x2, x3,
                                               Wih1, Whh1, bi1, bh1,
                                               Wih2, Whh2, bi2, bh2,
                                               Wih3, Whh3, bi3, bh3, hws);
    fc_kernel<<<256, 64, 0, stream>>>(hws, fcW, fcb, (float*)d_out);
}

// Round 4
// 2555.114 us; speedup vs baseline: 2.1916x; 1.0070x over previous
//
#include <hip/hip_runtime.h>

#define HID 100
#define TT  1024
#define BPW 4     // batches per workgroup (4*64 = 256 exactly -> no tail)
#define WPL 64    // workgroups per LSTM
#define NTHR 512

typedef float f32x4 __attribute__((ext_vector_type(4)));

__device__ __forceinline__ float sigf(float x) { return 1.f / (1.f + __expf(-x)); }
__device__ __forceinline__ float tanhf_fast(float x) { return 2.f / (1.f + __expf(-2.f * x)) - 1.f; }

// One WG = 4 batch chains of one LSTM, 512 threads (8 waves), grid 192.
// R2 lesson: named float4 consts were STILL re-loaded from L2 every step
// (VGPR_Count=68) -> ~200KB/step/CU of L2 traffic was the bottleneck.
// Fix: opaque asm pin on each weight quad -> value originates from the asm,
// compiler cannot rematerialize the load; weights stay in VGPRs for the loop.
__global__ __launch_bounds__(NTHR, 1) void lstm3_kernel(
    const float* __restrict__ x1, const float* __restrict__ x2, const float* __restrict__ x3,
    const float* __restrict__ Wih1, const float* __restrict__ Whh1, const float* __restrict__ bi1, const float* __restrict__ bh1,
    const float* __restrict__ Wih2, const float* __restrict__ Whh2, const float* __restrict__ bi2, const float* __restrict__ bh2,
    const float* __restrict__ Wih3, const float* __restrict__ Whh3, const float* __restrict__ bi3, const float* __restrict__ bh3,
    float* __restrict__ hws)
{
    const int wg    = blockIdx.x;
    const int L     = wg / WPL;
    const int bbase = (wg % WPL) * BPW;
    const int tid   = threadIdx.x;

    const float* x   = (L == 0) ? x1   : (L == 1) ? x2   : x3;
    const float* Wih = (L == 0) ? Wih1 : (L == 1) ? Wih2 : Wih3;
    const float* Whh = (L == 0) ? Whh1 : (L == 1) ? Whh2 : Whh3;
    const float* bi  = (L == 0) ? bi1  : (L == 1) ? bi2  : bi3;
    const float* bh  = (L == 0) ? bh1  : (L == 1) ? bh2  : bh3;

    __shared__ __align__(16) float x_lds[BPW][TT][4];   // 64 KiB
    __shared__ __align__(16) float h_lds[2][BPW][HID];  // 3.2 KiB double-buffered
    __shared__ __align__(16) float g_lds[BPW][4][HID];  // 6.4 KiB slot-major

    // ---- one-time x slab preload (coalesced float4) ----
    for (int i = tid; i < BPW * TT; i += NTHR) {
        const int b = i / TT, t = i % TT;
        ((f32x4*)x_lds)[i] = *(const f32x4*)(x + ((size_t)(bbase + b) * TT + t) * 4);
    }
    for (int i = tid; i < BPW * HID; i += NTHR) ((float*)h_lds[0])[i] = 0.f;

    // ---- row ownership ----
    const int  wave = tid >> 6, lane = tid & 63;
    const bool gth  = lane < 50;
    const int  row  = wave * 50 + lane;          // semantic row (valid if gth)
    const int  rowc = wave * 50 + min(lane, 49); // clamped row for safe loads
    const int  slot = row / 100;                 // gate slot / update batch (0..3)
    const int  cell = row % 100;                 // cell index  / update cell

    // ---- W_hh row: 25 quads, loaded then PINNED into VGPRs ----
    const f32x4* wp = (const f32x4*)(Whh + (size_t)rowc * HID);
    f32x4 W0  = wp[0],  W1  = wp[1],  W2  = wp[2],  W3  = wp[3],  W4  = wp[4];
    f32x4 W5  = wp[5],  W6  = wp[6],  W7  = wp[7],  W8  = wp[8],  W9  = wp[9];
    f32x4 W10 = wp[10], W11 = wp[11], W12 = wp[12], W13 = wp[13], W14 = wp[14];
    f32x4 W15 = wp[15], W16 = wp[16], W17 = wp[17], W18 = wp[18], W19 = wp[19];
    f32x4 W20 = wp[20], W21 = wp[21], W22 = wp[22], W23 = wp[23], W24 = wp[24];

    f32x4 wi   = *(const f32x4*)(Wih + (size_t)rowc * 4);
    float bias = bi[rowc] + bh[rowc];

    // Opaque pins: values now originate from asm -> cannot be re-loaded.
    asm volatile("" : "+v"(W0),  "+v"(W1),  "+v"(W2),  "+v"(W3),  "+v"(W4));
    asm volatile("" : "+v"(W5),  "+v"(W6),  "+v"(W7),  "+v"(W8),  "+v"(W9));
    asm volatile("" : "+v"(W10), "+v"(W11), "+v"(W12), "+v"(W13), "+v"(W14));
    asm volatile("" : "+v"(W15), "+v"(W16), "+v"(W17), "+v"(W18), "+v"(W19));
    asm volatile("" : "+v"(W20), "+v"(W21), "+v"(W22), "+v"(W23), "+v"(W24));
    asm volatile("" : "+v"(wi), "+v"(bias));

    float cc = 0.f, hh = 0.f;   // state of update job (batch=slot, cell)

    __syncthreads();

#define GSTEP(C, WV) do {                                              \
        const f32x4 h0_ = *(const f32x4*)&h_lds[cur][0][4*(C)];        \
        const f32x4 h1_ = *(const f32x4*)&h_lds[cur][1][4*(C)];        \
        const f32x4 h2_ = *(const f32x4*)&h_lds[cur][2][4*(C)];        \
        const f32x4 h3_ = *(const f32x4*)&h_lds[cur][3][4*(C)];        \
        a0 += WV.x * h0_.x; a0 += WV.y * h0_.y; a0 += WV.z * h0_.z; a0 += WV.w * h0_.w; \
        a1 += WV.x * h1_.x; a1 += WV.y * h1_.y; a1 += WV.z * h1_.z; a1 += WV.w * h1_.w; \
        a2 += WV.x * h2_.x; a2 += WV.y * h2_.y; a2 += WV.z * h2_.z; a2 += WV.w * h2_.w; \
        a3 += WV.x * h3_.x; a3 += WV.y * h3_.y; a3 += WV.z * h3_.z; a3 += WV.w * h3_.w; \
    } while (0)

#pragma unroll 1
    for (int st = 0; st < TT; ++st) {
        const int cur = st & 1;

        const f32x4 xb0 = *(const f32x4*)&x_lds[0][st][0];
        const f32x4 xb1 = *(const f32x4*)&x_lds[1][st][0];
        const f32x4 xb2 = *(const f32x4*)&x_lds[2][st][0];
        const f32x4 xb3 = *(const f32x4*)&x_lds[3][st][0];
        float a0 = bias + wi.x * xb0.x + wi.y * xb0.y + wi.z * xb0.z + wi.w * xb0.w;
        float a1 = bias + wi.x * xb1.x + wi.y * xb1.y + wi.z * xb1.z + wi.w * xb1.w;
        float a2 = bias + wi.x * xb2.x + wi.y * xb2.y + wi.z * xb2.z + wi.w * xb2.w;
        float a3 = bias + wi.x * xb3.x + wi.y * xb3.y + wi.z * xb3.z + wi.w * xb3.w;

        GSTEP(0,  W0);  GSTEP(1,  W1);  GSTEP(2,  W2);  GSTEP(3,  W3);  GSTEP(4,  W4);
        GSTEP(5,  W5);  GSTEP(6,  W6);  GSTEP(7,  W7);  GSTEP(8,  W8);  GSTEP(9,  W9);
        GSTEP(10, W10); GSTEP(11, W11); GSTEP(12, W12); GSTEP(13, W13); GSTEP(14, W14);
        GSTEP(15, W15); GSTEP(16, W16); GSTEP(17, W17); GSTEP(18, W18); GSTEP(19, W19);
        GSTEP(20, W20); GSTEP(21, W21); GSTEP(22, W22); GSTEP(23, W23); GSTEP(24, W24);

        if (gth) {
            g_lds[0][slot][cell] = a0;
            g_lds[1][slot][cell] = a1;
            g_lds[2][slot][cell] = a2;
            g_lds[3][slot][cell] = a3;
        }
        __syncthreads();

        if (gth) {
            const float gi = g_lds[slot][0][cell];
            const float gf = g_lds[slot][1][cell];
            const float gg = g_lds[slot][2][cell];
            const float go = g_lds[slot][3][cell];
            cc = sigf(gf) * cc + sigf(gi) * tanhf_fast(gg);
            hh = sigf(go) * tanhf_fast(cc);
            h_lds[cur ^ 1][slot][cell] = hh;
        }
        __syncthreads();
    }
#undef GSTEP

    // final h -> workspace [b_global][300], column L*100 + cell
    if (gth) hws[(size_t)(bbase + slot) * 300 + L * HID + cell] = hh;
}

// out[b][o] = relu(fc_b[o] + sum_j h[b][j] * fc_W[o][j]),  j < 300, o < 12
__global__ __launch_bounds__(64, 1) void fc_kernel(
    const float* __restrict__ hws, const float* __restrict__ fcW,
    const float* __restrict__ fcb, float* __restrict__ out)
{
    const int b = blockIdx.x, lane = threadIdx.x;
    float hv[5];
#pragma unroll
    for (int c = 0; c < 5; c++) {
        const int j = lane + 64 * c;
        hv[c] = (j < 300) ? hws[b * 300 + j] : 0.f;
    }
#pragma unroll
    for (int o = 0; o < 12; o++) {
        float a = 0.f;
#pragma unroll
        for (int c = 0; c < 5; c++) {
            const int j = lane + 64 * c;
            const float wv = (j < 300) ? fcW[o * 300 + j] : 0.f;
            a += hv[c] * wv;
        }
#pragma unroll
        for (int off = 32; off > 0; off >>= 1) a += __shfl_xor(a, off, 64);
        if (lane == 0) out[b * 12 + o] = fmaxf(a + fcb[o], 0.f);
    }
}

extern "C" void kernel_launch(void* const* d_in, const int* in_sizes, int n_in,
                              void* d_out, int out_size, void* d_ws, size_t ws_size,
                              hipStream_t stream)
{
    const float* x1   = (const float*)d_in[0];
    const float* x2   = (const float*)d_in[1];
    const float* x3   = (const float*)d_in[2];
    const float* Wih1 = (const float*)d_in[3];
    const float* Whh1 = (const float*)d_in[4];
    const float* bi1  = (const float*)d_in[5];
    const float* bh1  = (const float*)d_in[6];
    const float* Wih2 = (const float*)d_in[7];
    const float* Whh2 = (const float*)d_in[8];
    const float* bi2  = (const float*)d_in[9];
    const float* bh2  = (const float*)d_in[10];
    const float* Wih3 = (const float*)d_in[11];
    const float* Whh3 = (const float*)d_in[12];
    const float* bi3  = (const float*)d_in[13];
    const float* bh3  = (const float*)d_in[14];
    const float* fcW  = (const float*)d_in[15];
    const float* fcb  = (const float*)d_in[16];

    float* hws = (float*)d_ws;  // 256*300 floats = 300 KiB

    lstm3_kernel<<<3 * WPL, NTHR, 0, stream>>>(x1, x2, x3,
                                               Wih1, Whh1, bi1, bh1,
                                               Wih2, Whh2, bi2, bh2,
                                               Wih3, Whh3, bi3, bh3, hws);
    fc_kernel<<<256, 64, 0, stream>>>(hws, fcW, fcb, (float*)d_out);
}